// Round 14
// baseline (141.044 us; speedup 1.0000x reference)
//
#include <hip/hip_runtime.h>

#define HH 384
#define WW 384
#define HWSZ (HH * WW)          // 147456
#define NPLANES 128             // 2 batch * 64 chan
#define CHN 64
#define VSTRIPS 4
#define STRIP_H 96              // HH / VSTRIPS
#define RING 42                 // minimal ring for G=6, lag=6 (span analysis)
#define RSTRIDE 416             // 16 left pad + 384 + 15 right pad (+1 align)
#define NACC 11
#define NSUP 22                 // 22 stage steps of 6 rows; compute lags 6
#define QP (HWSZ / 4)           // 36864 float4 per plane
#define NINQ (NPLANES * QP)     // 4,718,592 input quads
#define OB 2048
#define OT 256
#define OITER (NINQ / (OB * OT))   // 9, exact

typedef float f4 __attribute__((ext_vector_type(4)));

// Rows [D0,D1) of a 6-row compute group; compile-time ring slots.
// FAST path: accumulate SB/SXB/SQB (invcy*invcx folded in ONCE at kernel end).
template<int BY0, bool FAST, int D0, int D1>
__device__ __forceinline__ void group6(const float (*ring)[RSTRIDE], int t, int Y,
        float& bs0, float& bs1, float& bs2, float& T1, float& T2,
        float Aa[3], float Bb[3], float Cc[3],
        float SB[3], float SX[3], float SQ[3], const float invcx[3]) {
#pragma unroll
    for (int dy = D0; dy < D1; ++dy) {
        const int sl = (BY0 + dy) % RING;
        const float* pr = &ring[sl][t];
        float xv = pr[16] - pr[15];          // recover x[y][t]
        T1 += xv;
        T2 = fmaf(xv, xv, T2);
        if (FAST) {
            SB[0] += bs0; SX[0] = fmaf(xv, bs0, SX[0]); SQ[0] = fmaf(bs0, bs0, SQ[0]);
            SB[1] += bs1; SX[1] = fmaf(xv, bs1, SX[1]); SQ[1] = fmaf(bs1, bs1, SQ[1]);
            SB[2] += bs2; SX[2] = fmaf(xv, bs2, SX[2]); SQ[2] = fmaf(bs2, bs2, SQ[2]);
        } else {
            const int y = Y + dy;
            const int W2S[3] = {3, 7, 15};
#pragma unroll
            for (int i = 0; i < 3; ++i) {
                int w2 = W2S[i];
                int chi = y + w2; if (chi > HH - 1) chi = HH - 1;
                int clo = y - w2; if (clo < 0) clo = 0;
                float invcy = __builtin_amdgcn_rcpf((float)(chi - clo + 1));
                float bsv = (i == 0) ? bs0 : ((i == 1) ? bs1 : bs2);
                float m = bsv * (invcy * invcx[i]);
                Aa[i] += m; Bb[i] = fmaf(xv, m, Bb[i]); Cc[i] = fmaf(m, m, Cc[i]);
            }
        }
        // advance to y+1: enter slots sl+{4,8,16}, leave slots sl-{3,7,15}
        const int e0 = (sl + 4) % RING, e1 = (sl + 8) % RING, e2 = (sl + 16) % RING;
        const int l0 = (sl + RING - 3) % RING, l1 = (sl + RING - 7) % RING,
                  l2 = (sl + RING - 15) % RING;
        const float* pe0 = &ring[e0][t]; const float* pl0 = &ring[l0][t];
        const float* pe1 = &ring[e1][t]; const float* pl1 = &ring[l1][t];
        const float* pe2 = &ring[e2][t]; const float* pl2 = &ring[l2][t];
        bs0 += (pe0[19] - pe0[12]) - (pl0[19] - pl0[12]);
        bs1 += (pe1[23] - pe1[8])  - (pl1[23] - pl1[8]);
        bs2 += (pe2[31] - pe2[0])  - (pl2[31] - pl2[0]);
    }
}

#define GROUP_CALL(BY, DA, DB)                                                   \
    do {                                                                         \
        if (fast) group6<BY, true, DA, DB>(ring, t, Y, bs0, bs1, bs2, T1, T2,    \
                                           Aa, Bb, Cc, SB, SX, SQ, invcx);       \
        else      group6<BY, false, DA, DB>(ring, t, Y, bs0, bs1, bs2, T1, T2,   \
                                            Aa, Bb, Cc, SB, SX, SQ, invcx);      \
    } while (0)

// Ring row layout: [0..15]=0 (P[-k]), [16+c]=P[c], [400..414]=P[383].
__global__ __launch_bounds__(384, 3) void stats_fused(const float* __restrict__ x,
                                                      float* __restrict__ partials) {
    __shared__ float ring[RING][RSTRIDE];   // 69,888 B -> 2 blocks/CU
    __shared__ float redbuf[6 * NACC];

    const int t = threadIdx.x;              // column 0..383
    const int lane = t & 63;
    const int wv = t >> 6;
    const int bid = blockIdx.x;
    const int p = bid >> 2;                 // plane
    const int s = bid & 3;                  // strip
    const int y0 = s * STRIP_H;
    const float* __restrict__ xp = x + (size_t)p * HWSZ;

    const int W2S[3] = {3, 7, 15};          // l=0 -> w7, l=1 -> w15, l=2 -> w31
    float invcx[3], fmul[3];
#pragma unroll
    for (int i = 0; i < 3; ++i) {
        int w2 = W2S[i];
        int hi = t + w2; if (hi > WW - 1) hi = WW - 1;
        int lo = t - w2; if (lo < 0) lo = 0;
        invcx[i] = 1.0f / (float)(hi - lo + 1);
        fmul[i] = invcx[i] * (1.0f / (float)(2 * w2 + 1));   // interior invcy folded
    }

    // zero the left pads once (staging never touches cols < 16)
    for (int idx = t; idx < RING * 16; idx += 384)
        ring[idx >> 4][idx & 15] = 0.f;

    float bs0 = 0.f, bs1 = 0.f, bs2 = 0.f;
    float Aa[3] = {0.f, 0.f, 0.f};
    float Bb[3] = {0.f, 0.f, 0.f};
    float Cc[3] = {0.f, 0.f, 0.f};
    float SB[3] = {0.f, 0.f, 0.f};
    float SX[3] = {0.f, 0.f, 0.f};
    float SQ[3] = {0.f, 0.f, 0.f};
    float T1 = 0.f, T2 = 0.f;

    // prefetch stage-step 0: wave wv handles row u = wv
    float2 A0 = {0,0}, A1 = {0,0}, A2 = {0,0};
    {
        int r = y0 - 16 + wv;
        if ((unsigned)r < (unsigned)HH) {
            const float* src = xp + (size_t)r * WW + lane * 6;
            A0 = *(const float2*)(src); A1 = *(const float2*)(src + 2); A2 = *(const float2*)(src + 4);
        }
    }

    for (int k = 0; k < NSUP; ++k) {
        const int u = 6 * k + wv;           // this wave's staged row index
        const int r = y0 - 16 + u;
        if (u <= 126) {
            int sl = u; if (sl >= 84) sl -= 84; if (sl >= 42) sl -= 42;
            float* dst = ring[sl];
            if ((unsigned)r < (unsigned)HH) {
                float s0 = A0.x, s1 = s0 + A0.y, s2 = s1 + A1.x;
                float s3 = s2 + A1.y, s4 = s3 + A2.x, s5 = s4 + A2.y;
                float tot = s5, e = tot;
#pragma unroll
                for (int d = 1; d < 64; d <<= 1) {
                    float uu = __shfl_up(e, d, 64);
                    if (lane >= d) e += uu;
                }
                e -= tot;                   // exclusive offset of lane totals
                float p383 = __shfl(s5 + e, 63, 64);
                float* dp = dst + 16 + lane * 6;
                *(float2*)(dp)     = make_float2(s0 + e, s1 + e);
                *(float2*)(dp + 2) = make_float2(s2 + e, s3 + e);
                *(float2*)(dp + 4) = make_float2(s4 + e, s5 + e);
                if (lane < 15) dst[400 + lane] = p383;   // right pad = P[383]
            } else {
                float* dp = dst + 16 + lane * 6;
                *(float2*)(dp)     = make_float2(0.f, 0.f);
                *(float2*)(dp + 2) = make_float2(0.f, 0.f);
                *(float2*)(dp + 4) = make_float2(0.f, 0.f);
                if (lane < 15) dst[400 + lane] = 0.f;
            }
        }
        if (k < NSUP - 1) {                 // issue next step's global loads NOW
            A0 = A1 = A2 = make_float2(0.f, 0.f);
            int rn = r + 6;
            if (u + 6 <= 126 && (unsigned)rn < (unsigned)HH) {
                const float* src = xp + (size_t)rn * WW + lane * 6;
                A0 = *(const float2*)(src); A1 = *(const float2*)(src + 2); A2 = *(const float2*)(src + 4);
            }
        }

        const int j = k - 6;
        const int Y = y0 + 6 * j;
        bool fast = false;
        if (j >= 0) {
            if (j == 0) {                   // prime box sums at y = y0 (slots 1..31, all old)
#pragma unroll
                for (int i = 0; i < 3; ++i) {
                    int w2 = W2S[i];
                    float sum = 0.f;
                    for (int rr = -w2; rr <= w2; ++rr) {
                        const float* pr = &ring[16 + rr][t];
                        sum += pr[16 + w2] - pr[15 - w2];
                    }
                    if (i == 0) bs0 = sum; else if (i == 1) bs1 = sum; else bs2 = sum;
                }
            }
            fast = (Y >= 15) && (Y <= 363);     // wave-uniform
            // PRE-BARRIER: rows dy=0..3 read only u <= 6j+35 (prior steps, disjoint
            // mod-42 from this step's writes) -> overlap scan + prefetch latency.
            switch (j % 7) {
            case 0: GROUP_CALL(16, 0, 4); break;
            case 1: GROUP_CALL(22, 0, 4); break;
            case 2: GROUP_CALL(28, 0, 4); break;
            case 3: GROUP_CALL(34, 0, 4); break;
            case 4: GROUP_CALL(40, 0, 4); break;
            case 5: GROUP_CALL(4,  0, 4); break;
            default: GROUP_CALL(10, 0, 4); break;
            }
        }
        __syncthreads();                    // one barrier per superstep (22 total)
        if (j >= 0) {
            // POST-BARRIER: rows dy=4,5 (need this step's staging)
            switch (j % 7) {
            case 0: GROUP_CALL(16, 4, 6); break;
            case 1: GROUP_CALL(22, 4, 6); break;
            case 2: GROUP_CALL(28, 4, 6); break;
            case 3: GROUP_CALL(34, 4, 6); break;
            case 4: GROUP_CALL(40, 4, 6); break;
            case 5: GROUP_CALL(4,  4, 6); break;
            default: GROUP_CALL(10, 4, 6); break;
            }
        }
    }

    // fold interior (fast-path) sums: m = bsum * fmul
#pragma unroll
    for (int i = 0; i < 3; ++i) {
        Aa[i] = fmaf(fmul[i], SB[i], Aa[i]);
        Bb[i] = fmaf(fmul[i], SX[i], Bb[i]);
        Cc[i] = fmaf(fmul[i] * fmul[i], SQ[i], Cc[i]);
    }

    // deterministic block reduction of the 11 accumulators
    float acc[NACC] = {Aa[0], Bb[0], Cc[0], Aa[1], Bb[1], Cc[1],
                       Aa[2], Bb[2], Cc[2], T1, T2};
#pragma unroll
    for (int q = 0; q < NACC; ++q) {
#pragma unroll
        for (int d = 32; d >= 1; d >>= 1) acc[q] += __shfl_xor(acc[q], d, 64);
    }
    if (lane == 0) {
#pragma unroll
        for (int q = 0; q < NACC; ++q) redbuf[wv * NACC + q] = acc[q];
    }
    __syncthreads();
    if (t < NACC) {
        float ssum = 0.f;
#pragma unroll
        for (int w = 0; w < 6; ++w) ssum += redbuf[w * NACC + t];
        partials[bid * NACC + t] = ssum;
    }
}

// ---- out: scales derived in-block from partials, then persistent grid-stride
// 1 coalesced read -> 4 nt-store streams (R8-validated memory shape). ----
__global__ __launch_bounds__(256) void out_kernel(const float* __restrict__ x,
                                                  const float* __restrict__ partials,
                                                  const float* __restrict__ tiny,
                                                  float* __restrict__ out) {
    __shared__ float ls[512];

    const unsigned stride = OB * OT;                 // 524288
    const unsigned base = blockIdx.x * OT + threadIdx.x;
    const f4* __restrict__ xq = (const f4*)x;
    f4* __restrict__ oq = (f4*)out;

    f4 v = xq[base];                                 // deep prefetch, in flight below

    {   // thread i computes 2 of the 512 scales (plane i>>1, l-pair i&1)
        int i = threadIdx.x;
        int pp = i >> 1;
        int half = i & 1;
        float acc[NACC];
#pragma unroll
        for (int q = 0; q < NACC; ++q) acc[q] = 0.f;
        for (int s = 0; s < VSTRIPS; ++s) {
#pragma unroll
            for (int q = 0; q < NACC; ++q)
                acc[q] += partials[(pp * VSTRIPS + s) * NACC + q];
        }
        const float Nf = (float)HWSZ;
        const float invNm1 = 1.0f / (float)(HWSZ - 1);
        float T1 = acc[9], T2 = acc[10];
        int b = pp >> 6, c = pp & 63;
        float thr = tiny[c] + 1e-6f;
#pragma unroll
        for (int li = 0; li < 2; ++li) {
            int l = half * 2 + li;
            float S, Q;
            if (l < 3) {
                S = T1 - acc[l * 3 + 0];
                Q = T2 - 2.f * acc[l * 3 + 1] + acc[l * 3 + 2];
            } else {
                S = T1;     // var(x - mean(x)) == var(x)
                Q = T2;
            }
            float var = (Q - S * S / Nf) * invNm1;
            float sd = sqrtf(fmaxf(var, 0.f));
            sd = fmaxf(sd, thr);
            ls[(b * 4 + l) * CHN + c] = 1.0f / sd;
        }
    }
    __syncthreads();

#pragma unroll
    for (int it = 0; it < OITER; ++it) {
        unsigned i = base + it * stride;
        f4 cur = v;
        if (it + 1 < OITER) v = xq[i + stride];      // prefetch next iter
        unsigned plane = i / QP;                     // wave-uniform (QP%64==0)
        unsigned q = i - plane * QP;
        unsigned b = plane >> 6, c = plane & 63;
        size_t o0 = (size_t)(b * 256 + c) * QP + q;  // l=0 output quad index
#pragma unroll
        for (int l = 0; l < 4; ++l) {
            f4 o = cur * ls[b * 256 + l * 64 + c];
            __builtin_nontemporal_store(o, oq + o0 + (size_t)l * 64 * QP);
        }
    }
}

extern "C" void kernel_launch(void* const* d_in, const int* in_sizes, int n_in,
                              void* d_out, int out_size, void* d_ws, size_t ws_size,
                              hipStream_t stream) {
    const float* x = (const float*)d_in[0];
    const float* tiny = (const float*)d_in[1];
    float* out = (float*)d_out;
    float* partials = (float*)d_ws;                  // 512*11 floats

    stats_fused<<<NPLANES * VSTRIPS, 384, 0, stream>>>(x, partials);
    out_kernel<<<OB, OT, 0, stream>>>(x, partials, tiny, out);
}

// Round 15
// 131.018 us; speedup vs baseline: 1.0765x; 1.0765x over previous
//
#include <hip/hip_runtime.h>

#define HH 384
#define WW 384
#define HWSZ (HH * WW)          // 147456
#define NPLANES 128             // 2 batch * 64 chan
#define CHN 64
#define VSTRIPS 4
#define STRIP_H 96              // HH / VSTRIPS
#define RING 42                 // minimal ring for G=6, lag=6 (span analysis)
#define RSTRIDE 416             // 16 left pad + 384 + 15 right pad (+1 align)
#define NACC 11
#define NSUP 22                 // 22 stage steps of 6 rows; compute lags 6
#define QP (HWSZ / 4)           // 36864 float4 per plane
#define NINQ (NPLANES * QP)     // 4,718,592 input quads
#define OB 2048
#define OT 256
#define OITER (NINQ / (OB * OT))   // 9, exact

typedef float f4 __attribute__((ext_vector_type(4)));

// 6-row compute group, COMPILE-TIME ring slots (BY0 = phase of (6j+16)%42).
// R13-validated form: fmul (interior invcy*invcx) applied per row in FAST path.
template<int BY0, bool FAST>
__device__ __forceinline__ void group6(const float (*ring)[RSTRIDE], int t, int Y,
        float& bs0, float& bs1, float& bs2, float& T1, float& T2,
        float Aa[3], float Bb[3], float Cc[3],
        const float fmul[3], const float invcx[3]) {
#pragma unroll
    for (int dy = 0; dy < 6; ++dy) {
        const int sl = (BY0 + dy) % RING;
        const float* pr = &ring[sl][t];
        float xv = pr[16] - pr[15];          // recover x[y][t]
        T1 += xv;
        T2 = fmaf(xv, xv, T2);
        if (FAST) {
            float m0 = bs0 * fmul[0], m1 = bs1 * fmul[1], m2 = bs2 * fmul[2];
            Aa[0] += m0; Bb[0] = fmaf(xv, m0, Bb[0]); Cc[0] = fmaf(m0, m0, Cc[0]);
            Aa[1] += m1; Bb[1] = fmaf(xv, m1, Bb[1]); Cc[1] = fmaf(m1, m1, Cc[1]);
            Aa[2] += m2; Bb[2] = fmaf(xv, m2, Bb[2]); Cc[2] = fmaf(m2, m2, Cc[2]);
        } else {
            const int y = Y + dy;
            const int W2S[3] = {3, 7, 15};
#pragma unroll
            for (int i = 0; i < 3; ++i) {
                int w2 = W2S[i];
                int chi = y + w2; if (chi > HH - 1) chi = HH - 1;
                int clo = y - w2; if (clo < 0) clo = 0;
                float invcy = __builtin_amdgcn_rcpf((float)(chi - clo + 1));
                float bsv = (i == 0) ? bs0 : ((i == 1) ? bs1 : bs2);
                float m = bsv * (invcy * invcx[i]);
                Aa[i] += m; Bb[i] = fmaf(xv, m, Bb[i]); Cc[i] = fmaf(m, m, Cc[i]);
            }
        }
        // advance to y+1: enter slots sl+{4,8,16}, leave slots sl-{3,7,15}
        const int e0 = (sl + 4) % RING, e1 = (sl + 8) % RING, e2 = (sl + 16) % RING;
        const int l0 = (sl + RING - 3) % RING, l1 = (sl + RING - 7) % RING,
                  l2 = (sl + RING - 15) % RING;
        const float* pe0 = &ring[e0][t]; const float* pl0 = &ring[l0][t];
        const float* pe1 = &ring[e1][t]; const float* pl1 = &ring[l1][t];
        const float* pe2 = &ring[e2][t]; const float* pl2 = &ring[l2][t];
        bs0 += (pe0[19] - pe0[12]) - (pl0[19] - pl0[12]);
        bs1 += (pe1[23] - pe1[8])  - (pl1[23] - pl1[8]);
        bs2 += (pe2[31] - pe2[0])  - (pl2[31] - pl2[0]);
    }
}

// Ring row layout: [0..15]=0 (P[-k]), [16+c]=P[c], [400..414]=P[383].
__global__ __launch_bounds__(384, 3) void stats_fused(const float* __restrict__ x,
                                                      float* __restrict__ partials) {
    __shared__ float ring[RING][RSTRIDE];   // 69,888 B -> 2 blocks/CU
    __shared__ float redbuf[6 * NACC];

    const int t = threadIdx.x;              // column 0..383
    const int lane = t & 63;
    const int wv = t >> 6;
    const int bid = blockIdx.x;
    const int p = bid >> 2;                 // plane
    const int s = bid & 3;                  // strip
    const int y0 = s * STRIP_H;
    const float* __restrict__ xp = x + (size_t)p * HWSZ;

    const int W2S[3] = {3, 7, 15};          // l=0 -> w7, l=1 -> w15, l=2 -> w31
    float invcx[3], fmul[3];
#pragma unroll
    for (int i = 0; i < 3; ++i) {
        int w2 = W2S[i];
        int hi = t + w2; if (hi > WW - 1) hi = WW - 1;
        int lo = t - w2; if (lo < 0) lo = 0;
        invcx[i] = 1.0f / (float)(hi - lo + 1);
        fmul[i] = invcx[i] * (1.0f / (float)(2 * w2 + 1));   // interior invcy folded
    }

    // zero the left pads once (staging never touches cols < 16)
    for (int idx = t; idx < RING * 16; idx += 384)
        ring[idx >> 4][idx & 15] = 0.f;

    float bs0 = 0.f, bs1 = 0.f, bs2 = 0.f;
    float Aa[3] = {0.f, 0.f, 0.f};
    float Bb[3] = {0.f, 0.f, 0.f};
    float Cc[3] = {0.f, 0.f, 0.f};
    float T1 = 0.f, T2 = 0.f;

    // prefetch stage-step 0: wave wv handles row u = wv
    float2 A0 = {0,0}, A1 = {0,0}, A2 = {0,0};
    {
        int r = y0 - 16 + wv;
        if ((unsigned)r < (unsigned)HH) {
            const float* src = xp + (size_t)r * WW + lane * 6;
            A0 = *(const float2*)(src); A1 = *(const float2*)(src + 2); A2 = *(const float2*)(src + 4);
        }
    }

    for (int k = 0; k < NSUP; ++k) {
        const int u = 6 * k + wv;           // this wave's staged row index
        const int r = y0 - 16 + u;
        if (u <= 126) {
            int sl = u; if (sl >= 84) sl -= 84; if (sl >= 42) sl -= 42;
            float* dst = ring[sl];
            if ((unsigned)r < (unsigned)HH) {
                float s0 = A0.x, s1 = s0 + A0.y, s2 = s1 + A1.x;
                float s3 = s2 + A1.y, s4 = s3 + A2.x, s5 = s4 + A2.y;
                float tot = s5, e = tot;
#pragma unroll
                for (int d = 1; d < 64; d <<= 1) {
                    float uu = __shfl_up(e, d, 64);
                    if (lane >= d) e += uu;
                }
                e -= tot;                   // exclusive offset of lane totals
                float p383 = __shfl(s5 + e, 63, 64);
                float* dp = dst + 16 + lane * 6;
                *(float2*)(dp)     = make_float2(s0 + e, s1 + e);
                *(float2*)(dp + 2) = make_float2(s2 + e, s3 + e);
                *(float2*)(dp + 4) = make_float2(s4 + e, s5 + e);
                if (lane < 15) dst[400 + lane] = p383;   // right pad = P[383]
            } else {
                float* dp = dst + 16 + lane * 6;
                *(float2*)(dp)     = make_float2(0.f, 0.f);
                *(float2*)(dp + 2) = make_float2(0.f, 0.f);
                *(float2*)(dp + 4) = make_float2(0.f, 0.f);
                if (lane < 15) dst[400 + lane] = 0.f;
            }
        }
        if (k < NSUP - 1) {                 // issue next step's global loads NOW;
            A0 = A1 = A2 = make_float2(0.f, 0.f);   // they stay in flight ACROSS the
            int rn = r + 6;                          // raw barrier (no vmcnt drain)
            if (u + 6 <= 126 && (unsigned)rn < (unsigned)HH) {
                const float* src = xp + (size_t)rn * WW + lane * 6;
                A0 = *(const float2*)(src); A1 = *(const float2*)(src + 2); A2 = *(const float2*)(src + 4);
            }
        }

        // Raw barrier: order LDS only (lgkmcnt), do NOT drain vmcnt — the
        // __syncthreads() form emits s_waitcnt vmcnt(0) which kills the
        // prefetch overlap (m97 barrier-drain stall). sched_barrier keeps the
        // compiler from hoisting post-barrier ds_reads above it (rule #18).
        asm volatile("s_waitcnt lgkmcnt(0)" ::: "memory");
        __builtin_amdgcn_s_barrier();
        __builtin_amdgcn_sched_barrier(0);

        int j = k - 6;
        if (j >= 0) {
            const int Y = y0 + 6 * j;
            if (j == 0) {                   // prime box sums at y = y0 (slots 1..31)
#pragma unroll
                for (int i = 0; i < 3; ++i) {
                    int w2 = W2S[i];
                    float sum = 0.f;
                    for (int rr = -w2; rr <= w2; ++rr) {
                        const float* pr = &ring[16 + rr][t];
                        sum += pr[16 + w2] - pr[15 - w2];
                    }
                    if (i == 0) bs0 = sum; else if (i == 1) bs1 = sum; else bs2 = sum;
                }
            }
            const bool fast = (Y >= 15) && (Y <= 363);     // wave-uniform
            switch (j % 7) {                // by0 = (16+6j)%42: {16,22,28,34,40,4,10}
            case 0:
                if (fast) group6<16, true >(ring, t, Y, bs0, bs1, bs2, T1, T2, Aa, Bb, Cc, fmul, invcx);
                else      group6<16, false>(ring, t, Y, bs0, bs1, bs2, T1, T2, Aa, Bb, Cc, fmul, invcx);
                break;
            case 1:
                if (fast) group6<22, true >(ring, t, Y, bs0, bs1, bs2, T1, T2, Aa, Bb, Cc, fmul, invcx);
                else      group6<22, false>(ring, t, Y, bs0, bs1, bs2, T1, T2, Aa, Bb, Cc, fmul, invcx);
                break;
            case 2:
                if (fast) group6<28, true >(ring, t, Y, bs0, bs1, bs2, T1, T2, Aa, Bb, Cc, fmul, invcx);
                else      group6<28, false>(ring, t, Y, bs0, bs1, bs2, T1, T2, Aa, Bb, Cc, fmul, invcx);
                break;
            case 3:
                if (fast) group6<34, true >(ring, t, Y, bs0, bs1, bs2, T1, T2, Aa, Bb, Cc, fmul, invcx);
                else      group6<34, false>(ring, t, Y, bs0, bs1, bs2, T1, T2, Aa, Bb, Cc, fmul, invcx);
                break;
            case 4:
                if (fast) group6<40, true >(ring, t, Y, bs0, bs1, bs2, T1, T2, Aa, Bb, Cc, fmul, invcx);
                else      group6<40, false>(ring, t, Y, bs0, bs1, bs2, T1, T2, Aa, Bb, Cc, fmul, invcx);
                break;
            case 5:
                if (fast) group6<4, true >(ring, t, Y, bs0, bs1, bs2, T1, T2, Aa, Bb, Cc, fmul, invcx);
                else      group6<4, false>(ring, t, Y, bs0, bs1, bs2, T1, T2, Aa, Bb, Cc, fmul, invcx);
                break;
            default:
                if (fast) group6<10, true >(ring, t, Y, bs0, bs1, bs2, T1, T2, Aa, Bb, Cc, fmul, invcx);
                else      group6<10, false>(ring, t, Y, bs0, bs1, bs2, T1, T2, Aa, Bb, Cc, fmul, invcx);
                break;
            }
        }
    }

    // deterministic block reduction of the 11 accumulators
    float acc[NACC] = {Aa[0], Bb[0], Cc[0], Aa[1], Bb[1], Cc[1],
                       Aa[2], Bb[2], Cc[2], T1, T2};
#pragma unroll
    for (int q = 0; q < NACC; ++q) {
#pragma unroll
        for (int d = 32; d >= 1; d >>= 1) acc[q] += __shfl_xor(acc[q], d, 64);
    }
    if (lane == 0) {
#pragma unroll
        for (int q = 0; q < NACC; ++q) redbuf[wv * NACC + q] = acc[q];
    }
    __syncthreads();
    if (t < NACC) {
        float ssum = 0.f;
#pragma unroll
        for (int w = 0; w < 6; ++w) ssum += redbuf[w * NACC + t];
        partials[bid * NACC + t] = ssum;
    }
}

// ---- out: scales derived in-block from partials (saves a dispatch), then
// persistent grid-stride: 1 coalesced read -> 4 nt-store streams (R8 shape). ----
__global__ __launch_bounds__(256) void out_kernel(const float* __restrict__ x,
                                                  const float* __restrict__ partials,
                                                  const float* __restrict__ tiny,
                                                  float* __restrict__ out) {
    __shared__ float ls[512];

    const unsigned stride = OB * OT;                 // 524288
    const unsigned base = blockIdx.x * OT + threadIdx.x;
    const f4* __restrict__ xq = (const f4*)x;
    f4* __restrict__ oq = (f4*)out;

    f4 v = xq[base];                                 // prefetch, in flight below

    {   // thread i computes 2 of the 512 scales (plane i>>1, l-pair i&1)
        int i = threadIdx.x;
        int pp = i >> 1;
        int half = i & 1;
        float acc[NACC];
#pragma unroll
        for (int q = 0; q < NACC; ++q) acc[q] = 0.f;
        for (int s = 0; s < VSTRIPS; ++s) {
#pragma unroll
            for (int q = 0; q < NACC; ++q)
                acc[q] += partials[(pp * VSTRIPS + s) * NACC + q];
        }
        const float Nf = (float)HWSZ;
        const float invNm1 = 1.0f / (float)(HWSZ - 1);
        float T1 = acc[9], T2 = acc[10];
        int b = pp >> 6, c = pp & 63;
        float thr = tiny[c] + 1e-6f;
#pragma unroll
        for (int li = 0; li < 2; ++li) {
            int l = half * 2 + li;
            float S, Q;
            if (l < 3) {
                S = T1 - acc[l * 3 + 0];
                Q = T2 - 2.f * acc[l * 3 + 1] + acc[l * 3 + 2];
            } else {
                S = T1;     // var(x - mean(x)) == var(x)
                Q = T2;
            }
            float var = (Q - S * S / Nf) * invNm1;
            float sd = sqrtf(fmaxf(var, 0.f));
            sd = fmaxf(sd, thr);
            ls[(b * 4 + l) * CHN + c] = 1.0f / sd;
        }
    }
    __syncthreads();

#pragma unroll
    for (int it = 0; it < OITER; ++it) {
        unsigned i = base + it * stride;
        f4 cur = v;
        if (it + 1 < OITER) v = xq[i + stride];      // prefetch next iter
        unsigned plane = i / QP;                     // wave-uniform (QP%64==0)
        unsigned q = i - plane * QP;
        unsigned b = plane >> 6, c = plane & 63;
        size_t o0 = (size_t)(b * 256 + c) * QP + q;  // l=0 output quad index
#pragma unroll
        for (int l = 0; l < 4; ++l) {
            f4 o = cur * ls[b * 256 + l * 64 + c];
            __builtin_nontemporal_store(o, oq + o0 + (size_t)l * 64 * QP);
        }
    }
}

extern "C" void kernel_launch(void* const* d_in, const int* in_sizes, int n_in,
                              void* d_out, int out_size, void* d_ws, size_t ws_size,
                              hipStream_t stream) {
    const float* x = (const float*)d_in[0];
    const float* tiny = (const float*)d_in[1];
    float* out = (float*)d_out;
    float* partials = (float*)d_ws;                  // 512*11 floats

    stats_fused<<<NPLANES * VSTRIPS, 384, 0, stream>>>(x, partials);
    out_kernel<<<OB, OT, 0, stream>>>(x, partials, tiny, out);
}